// Round 5
// baseline (297.035 us; speedup 1.0000x reference)
//
#include <hip/hip_runtime.h>
#include <stdint.h>

typedef unsigned short u16;
typedef __attribute__((ext_vector_type(8))) short bf16x8;
typedef __attribute__((ext_vector_type(4))) float f32x4;

static const int N_NODES = 131072;   // B*T*NN = 128*128*8
static const int N_EDGES = 1048576;

__device__ __forceinline__ float u2f(u16 u){
  union{uint32_t i; float f;} w; w.i = ((uint32_t)u)<<16; return w.f;
}
__device__ __forceinline__ u16 f2u(float f){
  union{float f; uint32_t u;} v; v.f=f;
  uint32_t u=v.u;
  u += 0x7fff + ((u>>16)&1);   // round-to-nearest-even
  return (u16)(u>>16);
}
__device__ __forceinline__ float bits2f(uint32_t b){
  union{uint32_t i; float f;} w; w.i = b; return w.f;
}
__device__ __forceinline__ float ldmix(const void* p, int i, int isbf){
  return isbf ? u2f(((const u16*)p)[i]) : ((const float*)p)[i];
}
// fast tanh: 1 - 2/(e^{2|x|}+1), sign restored. err ~1e-7 << bf16 quantum.
__device__ __forceinline__ float ftanh(float x){
  float ax = fabsf(x);
  float e  = __expf(ax + ax);
  float r  = 1.f - __fdividef(2.f, e + 1.f);
  return copysignf(r, x);
}

// ---------------- hist + fused dtype-detect + accumulator zeroing ----------------
__global__ __launch_bounds__(256) void k_hist(const int* __restrict__ dst, int* __restrict__ H,
                                              const uint32_t* __restrict__ x, int* __restrict__ flag,
                                              float* __restrict__ stats1, float* __restrict__ stats2,
                                              float* __restrict__ zacc){
  __shared__ int h[256];
  __shared__ int dcnt;
  int tid = threadIdx.x;
  h[tid] = 0;
  if (blockIdx.x == 0){
    if (tid == 0){ dcnt = 0; flag[16] = 0; }   // flag[16] = bnfuse-final done-counter
    for (int i=tid; i<512; i+=256){ stats1[i] = 0.f; stats2[i] = 0.f; }
    for (int i=tid; i<1024; i+=256) zacc[i] = 0.f;
  }
  __syncthreads();
  if (blockIdx.x == 0){
    uint32_t e = (x[tid]>>7) & 0xFFu;
    int ok = (e >= 0x6Fu && e <= 0x85u) ? 1 : 0;
    unsigned long long m = __ballot(ok);
    if ((tid & 63) == 0) atomicAdd(&dcnt, (int)__popcll(m));
    __syncthreads();
    if (tid == 0) *flag = (dcnt >= 128) ? 1 : 0;
  }
  int base = blockIdx.x*4096;
  #pragma unroll
  for (int i=0;i<16;i++){
    int e2 = base + i*256 + tid;
    atomicAdd(&h[(dst[e2] & (N_NODES-1))>>9], 1);
  }
  __syncthreads();
  H[blockIdx.x*256 + tid] = h[tid];
}

// ---- combined weight-fold helper (unchanged math) ----
__device__ __forceinline__ void wcomb_one(int Kin, const void* gW, const void* gb, const void* tw,
                                          int isbf, u16* Wtb, float* braw, int r, int co){
  if (r < 3*Kin){
    int k = r / Kin, j = r - (r/Kin)*Kin;
    float acc = 0.f;
    for (int c=0; c<64; c++)
      acc += ldmix(gW, j*64+c, isbf) * ldmix(tw, co*192 + c*3 + k, isbf);
    Wtb[co*(3*Kin) + r] = f2u(acc);
  } else {
    int k = r - 3*Kin;
    float acc = 0.f;
    for (int c=0; c<64; c++)
      acc += ldmix(gb, c, isbf) * ldmix(tw, co*192 + c*3 + k, isbf);
    braw[k*64 + co] = acc;
  }
}

// ---------------- column scan (blocks 0..255) + weight-fold (blocks 256..361) ----------------
__global__ __launch_bounds__(256) void k_colscan_w(const int* __restrict__ H, int* __restrict__ P,
                                                   int* __restrict__ bt,
                                                   const void* __restrict__ g1w, const void* __restrict__ g1b,
                                                   const void* __restrict__ t1w,
                                                   const void* __restrict__ g2w, const void* __restrict__ g2b,
                                                   const void* __restrict__ t2w,
                                                   const void* __restrict__ o1w, const void* __restrict__ o2w,
                                                   const int* __restrict__ flag,
                                                   u16* __restrict__ Wtb1, float* __restrict__ braw1,
                                                   u16* __restrict__ Wtb2, float* __restrict__ braw2,
                                                   u16* __restrict__ owb1, u16* __restrict__ owb2){
  int tid = threadIdx.x;
  if (blockIdx.x < 256){
    __shared__ int sc[256];
    int b = blockIdx.x;
    int v = H[tid*256 + b];
    sc[tid] = v; __syncthreads();
    for (int d=1; d<256; d<<=1){
      int o = (tid>=d) ? sc[tid-d] : 0; __syncthreads();
      sc[tid] += o; __syncthreads();
    }
    P[tid*256 + b] = sc[tid] - v;
    if (tid==255) bt[b] = sc[255];
  } else {
    int isbf = *flag;
    int r = (blockIdx.x - 256)*4 + (tid>>6);
    int co = tid & 63;
    if (r >= 422) return;
    if (r < 99) wcomb_one(32, g1w, g1b, t1w, isbf, Wtb1, braw1, r, co);
    else if (r < 294) wcomb_one(64, g2w, g2b, t2w, isbf, Wtb2, braw2, r-99, co);
    else if (r < 358){
      int row = r - 294;
      owb1[row*64 + co] = f2u(ldmix(o1w, row*64 + co, isbf));
    } else {
      int row = r - 358;
      owb2[row*64 + co] = f2u(ldmix(o2w, row*64 + co, isbf));
    }
  }
}

__global__ __launch_bounds__(256) void k_scatter2(const int* __restrict__ src, const int* __restrict__ dst,
                                                  const int* __restrict__ P, const int* __restrict__ bt,
                                                  uint32_t* __restrict__ ebuf){
  __shared__ int cu[256], sc[256];
  int tid = threadIdx.x;
  int v = bt[tid];
  sc[tid] = v; __syncthreads();
  for (int d=1; d<256; d<<=1){
    int o = (tid>=d) ? sc[tid-d] : 0; __syncthreads();
    sc[tid] += o; __syncthreads();
  }
  cu[tid] = (sc[tid] - v) + P[blockIdx.x*256 + tid];   // bb[tid] + P
  __syncthreads();
  int base = blockIdx.x*4096;
  #pragma unroll
  for (int i=0;i<16;i++){
    int e = base + i*256 + tid;
    int s = src[e] & (N_NODES-1);
    int d = dst[e] & (N_NODES-1);
    int pos = atomicAdd(&cu[d>>9], 1);           // LDS atomic only
    ebuf[pos] = (uint32_t)s | ((uint32_t)(d & 511) << 17);
  }
}

// per-bucket counting sort + offs/deg/dinv + fused dinv-prescale of x -> bf16 (F=32)
__global__ __launch_bounds__(512) void k_bsort2(const uint32_t* __restrict__ ebuf, const int* __restrict__ bt,
                                                const void* __restrict__ x, const int* __restrict__ flag,
                                                int* __restrict__ adj, int* __restrict__ offs,
                                                int* __restrict__ deg, float* __restrict__ dinv,
                                                u16* __restrict__ Bout){
  __shared__ uint32_t ein[5120], outs[5120];
  __shared__ int hist[512], sc[512], cu[512];
  __shared__ int sct[256];
  __shared__ float dv[512];
  int b = blockIdx.x, tid = threadIdx.x;
  if (tid < 256){ sct[tid] = bt[tid]; }
  __syncthreads();
  for (int d=1; d<256; d<<=1){
    int o = (tid < 256 && tid>=d) ? sct[tid-d] : 0; __syncthreads();
    if (tid < 256) sct[tid] += o; __syncthreads();
  }
  int lo = sct[b] - bt[b], hi = sct[b];
  int cnt = hi - lo; if (cnt > 5120) cnt = 5120; if (cnt < 0) cnt = 0;
  hist[tid] = 0;
  __syncthreads();
  for (int i=tid; i<cnt; i+=512){
    uint32_t p = ebuf[lo+i];
    ein[i] = p;
    atomicAdd(&hist[(p>>17)&511], 1);
  }
  __syncthreads();
  sc[tid] = hist[tid];
  __syncthreads();
  for (int d=1; d<512; d<<=1){
    int v = (tid>=d) ? sc[tid-d] : 0;
    __syncthreads();
    sc[tid] += v;
    __syncthreads();
  }
  {
    int ex = sc[tid] - hist[tid];
    int node = b*512 + tid;
    offs[node] = lo + ex;
    deg[node]  = hist[tid];
    float rs = rsqrtf((float)hist[tid] + 1.0f);
    dinv[node] = rs;
    dv[tid] = rs;
    cu[tid] = ex;
  }
  __syncthreads();
  for (int i=tid; i<cnt; i+=512){
    uint32_t p = ein[i];
    int pos = atomicAdd(&cu[(p>>17)&511], 1);
    outs[pos] = p & 0x1FFFFu;
  }
  __syncthreads();
  for (int i=tid; i<cnt; i+=512) adj[lo+i] = (int)outs[i];
  int isbf = *flag;
  {
    uint32_t* Bd = (uint32_t*)Bout;
    for (int u=tid; u<8192; u+=512){
      int nl = u>>4, jd = u&15;                  // 16 u32-pairs per 32-col row
      int half = ((b<<9) + nl)*16 + jd;
      float x0, x1;
      if (isbf){
        uint32_t pr = ((const uint32_t*)x)[half];
        x0 = bits2f(pr<<16); x1 = bits2f(pr & 0xFFFF0000u);
      } else {
        float2 f2 = ((const float2*)x)[half];
        x0 = f2.x; x1 = f2.y;
      }
      float d = dv[nl];
      Bd[half] = (uint32_t)f2u(x0*d) | ((uint32_t)f2u(x1*d) << 16);
    }
  }
}

__device__ __forceinline__ void acc16(uint4 a, float* acc){
  acc[0] += bits2f(a.x<<16); acc[1] += bits2f(a.x&0xFFFF0000u);
  acc[2] += bits2f(a.y<<16); acc[3] += bits2f(a.y&0xFFFF0000u);
  acc[4] += bits2f(a.z<<16); acc[5] += bits2f(a.z&0xFFFF0000u);
  acc[6] += bits2f(a.w<<16); acc[7] += bits2f(a.w&0xFFFF0000u);
}

// =====================================================================================
// k_gconv: fused GCN-aggregate + temporal-conv MFMA + BN stats.
// R5: adjacency indices for all 66 rows are cooperatively staged into LDS first
// (block's adj region is a contiguous ~20KB bucket window -> 1-2 latency rounds),
// removing the serial adj-load level from every row's gather chain.
// =====================================================================================
template<int Kin>
__global__ __launch_bounds__(256) void k_gconv(
    const u16* __restrict__ Xs, const int* __restrict__ adj, const int* __restrict__ offs,
    const int* __restrict__ deg, const float* __restrict__ dinv,
    const u16* __restrict__ Wtb, const float* __restrict__ braw, const void* __restrict__ tb,
    const int* __restrict__ flag, u16* __restrict__ out, float* __restrict__ stats){
  constexpr int K   = 3*Kin;
  constexpr int SA  = Kin + 8;
  constexpr int CH  = Kin/8;           // 16B chunks per row
  constexpr int GPW = 64/CH;           // rows per wave pass
  __shared__ alignas(16) u16 At[66*SA];
  __shared__ int adjc[66*16];
  __shared__ float ball[64], bs0[64], bs2[64];
  __shared__ float wsum[4][64], wsum2[4][64];

  int isbf = *flag;
  int bid = blockIdx.x;
  int b = bid>>4, rem = bid&15, v = rem>>1, th = rem&1;
  const int tid = threadIdx.x;
  int wv_ = tid >> 6, lane = tid & 63;
  int q = lane >> 4, l16 = lane & 15;
  int ltb0 = wv_ * 16;
  int g = lane / CH, kch = lane % CH;
  const uint4* X4 = (const uint4*)Xs;

  if (tid < 64){
    float b0=braw[tid], b1=braw[64+tid], b2=braw[128+tid];
    ball[tid] = ldmix(tb, tid, isbf) + b0 + b1 + b2;
    bs0[tid] = b0; bs2[tid] = b2;
  }

  // ---- stage adj indices for all rows into LDS (coalesced bucket window) ----
  for (int u = tid; u < 66*16; u += 256){
    int row = u >> 4, j = u & 15;
    int t = th*64 + row - 1;
    int a = 0;
    if (t >= 0 && t < 128){
      int n = (b*128 + t)*8 + v;
      int o = offs[n] & (N_EDGES-1);
      int ao = o + j; ao = (ao > N_EDGES-1) ? (N_EDGES-1) : ao;
      a = adj[ao];
    }
    adjc[u] = a;
  }
  __syncthreads();

  // ---- fused aggregation: build At rows (bit-identical values to the split kernel) ----
  for (int row = wv_*GPW + g; row < 66; row += 4*GPW){
    int t = th*64 + row - 1;
    uint4 rv = {0,0,0,0};
    if (t >= 0 && t < 128){
      int n = (b*128 + t)*8 + v;
      int o = offs[n] & (N_EDGES-1);
      int cnt = min(deg[n], 8192);
      float dvv = dinv[n];
      float acc[8] = {0,0,0,0,0,0,0,0};
      acc16(X4[(size_t)n*CH + kch], acc);
      // fast path: one masked 16-wide MLP batch, indices from LDS (no global adj dep)
      {
        int idx[16];
        #pragma unroll
        for (int j=0; j<16; j++){
          int ai = adjc[(row<<4) + j] & (N_NODES-1);
          idx[j] = (j < cnt) ? ai : n;          // inactive -> self row (L1-hot)
        }
        uint4 av[16];
        #pragma unroll
        for (int j=0; j<16; j++) av[j] = X4[(size_t)idx[j]*CH + kch];
        #pragma unroll
        for (int j=0; j<16; j++){
          uint4 tv = av[j];
          bool act = (j < cnt);
          tv.x = act ? tv.x : 0u; tv.y = act ? tv.y : 0u;
          tv.z = act ? tv.z : 0u; tv.w = act ? tv.w : 0u;   // +0.0f adds are bit-exact
          acc16(tv, acc);
        }
      }
      int e = (cnt < 16) ? cnt : 16;
      // rare deg>16 continuation (verbatim old batch structure, same order)
      for (; e+8 <= cnt; e += 8){
        int i0 = adj[o+e+0] & (N_NODES-1);
        int i1 = adj[o+e+1] & (N_NODES-1);
        int i2 = adj[o+e+2] & (N_NODES-1);
        int i3 = adj[o+e+3] & (N_NODES-1);
        int i4 = adj[o+e+4] & (N_NODES-1);
        int i5 = adj[o+e+5] & (N_NODES-1);
        int i6 = adj[o+e+6] & (N_NODES-1);
        int i7 = adj[o+e+7] & (N_NODES-1);
        uint4 a0 = X4[(size_t)i0*CH + kch];
        uint4 a1 = X4[(size_t)i1*CH + kch];
        uint4 a2 = X4[(size_t)i2*CH + kch];
        uint4 a3 = X4[(size_t)i3*CH + kch];
        uint4 a4 = X4[(size_t)i4*CH + kch];
        uint4 a5 = X4[(size_t)i5*CH + kch];
        uint4 a6 = X4[(size_t)i6*CH + kch];
        uint4 a7 = X4[(size_t)i7*CH + kch];
        acc16(a0, acc); acc16(a1, acc); acc16(a2, acc); acc16(a3, acc);
        acc16(a4, acc); acc16(a5, acc); acc16(a6, acc); acc16(a7, acc);
      }
      if (e+4 <= cnt){
        int i0 = adj[o+e+0] & (N_NODES-1);
        int i1 = adj[o+e+1] & (N_NODES-1);
        int i2 = adj[o+e+2] & (N_NODES-1);
        int i3 = adj[o+e+3] & (N_NODES-1);
        uint4 a0 = X4[(size_t)i0*CH + kch];
        uint4 a1 = X4[(size_t)i1*CH + kch];
        uint4 a2 = X4[(size_t)i2*CH + kch];
        uint4 a3 = X4[(size_t)i3*CH + kch];
        acc16(a0, acc); acc16(a1, acc); acc16(a2, acc); acc16(a3, acc);
        e += 4;
      }
      for (; e < cnt; e++){
        int s = adj[o+e] & (N_NODES-1);
        uint4 a = X4[(size_t)s*CH + kch];
        acc16(a, acc);
      }
      rv.x = (uint32_t)f2u(acc[0]*dvv) | ((uint32_t)f2u(acc[1]*dvv) << 16);
      rv.y = (uint32_t)f2u(acc[2]*dvv) | ((uint32_t)f2u(acc[3]*dvv) << 16);
      rv.z = (uint32_t)f2u(acc[4]*dvv) | ((uint32_t)f2u(acc[5]*dvv) << 16);
      rv.w = (uint32_t)f2u(acc[6]*dvv) | ((uint32_t)f2u(acc[7]*dvv) << 16);
    }
    *(uint4*)&At[row*SA + kch*8] = rv;
  }
  __syncthreads();

  // ---- temporal-conv MFMA (verbatim from k_tconv3) ----
  f32x4 acc4[4];
  #pragma unroll
  for (int nt=0; nt<4; nt++) acc4[nt] = (f32x4){0.f,0.f,0.f,0.f};
  #pragma unroll
  for (int s=0; s<K/32; s++){
    int kk2 = (32*s)/Kin;
    int j0 = 32*s - kk2*Kin;
    int col = j0 + q*8;
    bf16x8 afr = *(const bf16x8*)&At[(ltb0 + l16 + kk2)*SA + col];
    bf16x8 bfr[4];
    #pragma unroll
    for (int nt=0; nt<4; nt++){
      int co = nt*16 + l16;
      bfr[nt] = *(const bf16x8*)&Wtb[co*K + 32*s + q*8];   // global, L1/L2-hot broadcast
    }
    #pragma unroll
    for (int nt=0; nt<4; nt++)
      acc4[nt] = __builtin_amdgcn_mfma_f32_16x16x32_bf16(afr, bfr[nt], acc4[nt], 0, 0, 0);
  }

  // ---- epilogue -> C16 (same bf16 round-trip) + BN stats ----
  float ls_[4] = {0,0,0,0}, ls2_[4] = {0,0,0,0};
  #pragma unroll
  for (int r=0; r<4; r++){
    int t = th*64 + ltb0 + q*4 + r;
    int base = (((b*128+t)*8+v)) << 6;
    #pragma unroll
    for (int nt=0; nt<4; nt++){
      int co = nt*16 + l16;
      float val = acc4[nt][r] + ball[co];
      if (t == 0)   val -= bs0[co];
      if (t == 127) val -= bs2[co];
      out[base + co] = f2u(val);
      ls_[nt] += val; ls2_[nt] += val*val;
    }
  }
  #pragma unroll
  for (int nt=0; nt<4; nt++){
    ls_[nt]  += __shfl_xor(ls_[nt], 16);  ls_[nt]  += __shfl_xor(ls_[nt], 32);
    ls2_[nt] += __shfl_xor(ls2_[nt], 16); ls2_[nt] += __shfl_xor(ls2_[nt], 32);
  }
  if (q == 0){
    #pragma unroll
    for (int nt=0; nt<4; nt++){
      wsum[wv_][nt*16 + l16]  = ls_[nt];
      wsum2[wv_][nt*16 + l16] = ls2_[nt];
    }
  }
  __syncthreads();
  if (tid < 64){
    float a = wsum[0][tid]+wsum[1][tid]+wsum[2][tid]+wsum[3][tid];
    float a2 = wsum2[0][tid]+wsum2[1][tid]+wsum2[2][tid]+wsum2[3][tid];
    int bank = (bid & 3) * 128;       // 4-way banked to cut atomic contention
    atomicAdd(&stats[bank + tid], a);
    atomicAdd(&stats[bank + 64 + tid], a2);
  }
}

// ---- BN-apply + ReLU + 1x1 conv via bf16 MFMA + tanh; grid 2048 (b,v,t-half) ----
// FINAL variant: last block (device-scope counter) also produces d_out (k_fin2 folded in).
template<bool FINAL>
__global__ __launch_bounds__(256) void k_bnfuse3(const u16* __restrict__ X, const float* __restrict__ stats,
                                                 const void* __restrict__ gam, const void* __restrict__ bet,
                                                 const u16* __restrict__ owb, const void* __restrict__ ob,
                                                 const int* __restrict__ flag, const float* __restrict__ presc,
                                                 u16* __restrict__ out16,
                                                 float* __restrict__ zacc, const void* __restrict__ rw,
                                                 const void* __restrict__ rb, void* __restrict__ dout,
                                                 int* __restrict__ dcnt){
  constexpr int SA = 72;
  __shared__ alignas(16) u16 Yl[64*SA];        // reused as Zl in epilogue
  __shared__ float kk[64], bsh[64], obs[64];
  __shared__ float rw_s[64];
  __shared__ float wred[4];
  __shared__ int islast;
  int isbf = *flag;
  int bid = blockIdx.x;
  int b = bid>>4, rem = bid&15, v = rem>>1, th = rem&1;
  const int tid = threadIdx.x;
  const float invM = 1.0f/131072.0f;

  if (tid < 64){
    int ci = tid;
    float s1 = stats[ci] + stats[128+ci] + stats[256+ci] + stats[384+ci];
    float s2 = stats[64+ci] + stats[192+ci] + stats[320+ci] + stats[448+ci];
    float mu = s1*invM;
    float var = s2*invM - mu*mu;
    float rs = rsqrtf(fmaxf(var, 0.f) + 1e-5f);
    float kv = rs*ldmix(gam, ci, isbf);
    kk[ci] = kv;
    bsh[ci] = ldmix(bet, ci, isbf) - mu*kv;
    obs[ci] = ldmix(ob, ci, isbf);
    if (FINAL){
      float s = 0.f;
      #pragma unroll
      for (int f=0; f<8; f++) s += ldmix(rw, ci*8 + f, isbf);
      rw_s[ci] = s;
    }
  }
  __syncthreads();
  {
    uint32_t* Yd = (uint32_t*)Yl;
    const uint32_t* Xg = (const uint32_t*)X;
    for (int u=tid; u<64*32; u+=256){
      int lt = u>>5, jd = u&31;
      int ci = jd<<1;
      int t = th*64 + lt;
      int rowbase = (((b*128+t)*8+v)) << 6;
      uint32_t pr = Xg[(rowbase>>1) + jd];
      float x0 = bits2f(pr<<16);
      float x1 = bits2f(pr & 0xFFFF0000u);
      float y0 = fmaxf(x0*kk[ci] + bsh[ci], 0.f);
      float y1 = fmaxf(x1*kk[ci+1] + bsh[ci+1], 0.f);
      Yd[lt*(SA/2) + jd] = (uint32_t)f2u(y0) | ((uint32_t)f2u(y1) << 16);
    }
  }
  __syncthreads();

  int wv_ = tid >> 6, lane = tid & 63;
  int q = lane >> 4, l16 = lane & 15;
  int ltb0 = wv_ * 16;

  f32x4 acc[4];
  #pragma unroll
  for (int nt=0; nt<4; nt++) acc[nt] = (f32x4){0.f,0.f,0.f,0.f};

  #pragma unroll
  for (int s=0; s<2; s++){
    int col = 32*s + q*8;
    bf16x8 afr = *(const bf16x8*)&Yl[(ltb0 + l16)*SA + col];
    bf16x8 bfr[4];
    #pragma unroll
    for (int nt=0; nt<4; nt++){
      int co = nt*16 + l16;
      bfr[nt] = *(const bf16x8*)&owb[co*64 + col];   // global, L1/L2-hot broadcast
    }
    #pragma unroll
    for (int nt=0; nt<4; nt++)
      acc[nt] = __builtin_amdgcn_mfma_f32_16x16x32_bf16(afr, bfr[nt], acc[nt], 0, 0, 0);
  }

  __syncthreads();   // MFMA reads of Yl done; reuse as Zl
  #pragma unroll
  for (int r=0; r<4; r++){
    int lt = ltb0 + q*4 + r;
    #pragma unroll
    for (int nt=0; nt<4; nt++){
      int co = nt*16 + l16;
      Yl[lt*SA + co] = f2u(acc[nt][r] + obs[co]);
    }
  }
  __syncthreads();
  if (!FINAL){
    // element (co, l): from t = th*64 + l; write row r = b*1024+co*16+v*2+th, col l
    for (int u=tid; u<4096; u+=256){
      int l = u & 63;
      int co = u >> 6;
      float z = ftanh(u2f(Yl[l*SA + co]));
      int r = (b<<10) + (co<<4) + (v<<1) + th;
      if (presc) z *= presc[r];       // lane-uniform
      out16[(r<<6) + l] = f2u(z);
    }
  } else {
    float zsum = 0.f;
    for (int u=tid; u<4096; u+=256){
      int l = u & 63;
      int co = u >> 6;
      float z = ftanh(u2f(Yl[l*SA + co]));
      zsum += z * rw_s[l];
    }
    for (int off=32; off; off>>=1) zsum += __shfl_down(zsum, off);
    if (lane == 0) wred[wv_] = zsum;
    __syncthreads();
    if (tid == 0){
      int base = (b<<3) + ((v&3)<<1) + th;
      atomicAdd(&zacc[base], wred[0] + wred[1] + wred[2] + wred[3]);
      __threadfence();                              // release zacc contribution
      int d = atomicAdd(dcnt, 1);
      islast = (d == 2047) ? 1 : 0;
    }
    __syncthreads();
    if (islast){
      __threadfence();                              // acquire all zacc contributions
      float rbs = 0.f;
      #pragma unroll
      for (int f=0; f<8; f++) rbs += ldmix(rb, f, isbf);
      for (int i = tid; i < 1024; i += 256){
        float val = zacc[i]*(1.0f/1024.0f) + rbs*0.125f;
        if (isbf) ((u16*)dout)[i] = f2u(val);
        else      ((float*)dout)[i] = val;
      }
    }
  }
}

extern "C" void kernel_launch(void* const* d_in, const int* in_sizes, int n_in,
                              void* d_out, int out_size, void* d_ws, size_t ws_size,
                              hipStream_t stream){
  (void)in_sizes; (void)n_in; (void)out_size; (void)ws_size;
  char* p = (char*)d_ws;
  auto alloc = [&](size_t bytes){ void* r = (void*)p; p += (bytes + 255) & ~(size_t)255; return r; };
  u16*   U1   = (u16*)  alloc(sizeof(u16)*(size_t)N_NODES*64);  // Bs16 ; later D16
  u16*   C16  = (u16*)  alloc(sizeof(u16)*(size_t)N_NODES*64);  // tconv out (bf16); ebuf alias
  int*   deg  = (int*)  alloc(sizeof(int)*N_NODES);
  float* dinv = (float*)alloc(sizeof(float)*N_NODES);
  int*   offs = (int*)  alloc(sizeof(int)*N_NODES);
  int*   adj  = (int*)  alloc(sizeof(int)*N_EDGES);
  int*   H    = (int*)  alloc(sizeof(int)*256*256);
  int*   P    = (int*)  alloc(sizeof(int)*256*256);
  int*   bt   = (int*)  alloc(sizeof(int)*256);
  float* stats1=(float*)alloc(sizeof(float)*512);
  float* stats2=(float*)alloc(sizeof(float)*512);
  int*   flag = (int*)  alloc(sizeof(int)*64);
  u16*   Wtb1 = (u16*)  alloc(sizeof(u16)*96*64);
  float* braw1= (float*)alloc(sizeof(float)*192);
  u16*   Wtb2 = (u16*)  alloc(sizeof(u16)*192*64);
  float* braw2= (float*)alloc(sizeof(float)*192);
  u16*   owb1 = (u16*)  alloc(sizeof(u16)*64*64);
  u16*   owb2 = (u16*)  alloc(sizeof(u16)*64*64);
  float* zacc = (float*)alloc(sizeof(float)*1024);
  uint32_t* ebuf = (uint32_t*)C16;           // alias: C16 dead until gconv1
  u16* Bs16 = U1;                            // N x 32 bf16 (prescaled x)
  u16* D16  = U1;                            // N x 64 bf16 (bnfuse1 out, prescaled; Bs16 dead by then)

  const void* x   = d_in[0];
  const int* edge = (const int*)d_in[1];
  const void* g1w = d_in[2];  const void* g1b = d_in[3];
  const void* t1w = d_in[4];  const void* t1b = d_in[5];
  const void* bn1g= d_in[6];  const void* bn1b= d_in[7];
  const void* o1w = d_in[8];  const void* o1b = d_in[9];
  const void* g2w = d_in[10]; const void* g2b = d_in[11];
  const void* t2w = d_in[12]; const void* t2b = d_in[13];
  const void* bn2g= d_in[14]; const void* bn2b= d_in[15];
  const void* o2w = d_in[16]; const void* o2b = d_in[17];
  const void* rw  = d_in[18]; const void* rb  = d_in[19];
  const int* src = edge;
  const int* dst = edge + N_EDGES;

  // graph prep
  k_hist     <<<256, 256, 0, stream>>>(dst, H, (const uint32_t*)x, flag, stats1, stats2, zacc);
  k_colscan_w<<<362, 256, 0, stream>>>(H, P, bt, g1w, g1b, t1w, g2w, g2b, t2w, o1w, o2w, flag,
                                       Wtb1, braw1, Wtb2, braw2, owb1, owb2);
  k_scatter2 <<<256, 256, 0, stream>>>(src, dst, P, bt, ebuf);
  k_bsort2   <<<256, 512, 0, stream>>>(ebuf, bt, x, flag, adj, offs, deg, dinv, Bs16);

  // ---- layer 1: fused agg+tconv, then BN+1x1+tanh ----
  k_gconv<32> <<<2048, 256, 0, stream>>>(Bs16, adj, offs, deg, dinv, Wtb1, braw1, t1b, flag, C16, stats1);
  k_bnfuse3<false><<<2048, 256, 0, stream>>>(C16, stats1, bn1g, bn1b, owb1, o1b, flag, dinv, D16,
                                             (float*)nullptr, (const void*)nullptr,
                                             (const void*)nullptr, (void*)nullptr, (int*)nullptr);

  // ---- layer 2: fused agg+tconv, then BN+1x1+tanh+reduce (+folded finish) ----
  k_gconv<64> <<<2048, 256, 0, stream>>>(D16, adj, offs, deg, dinv, Wtb2, braw2, t2b, flag, C16, stats2);
  k_bnfuse3<true><<<2048, 256, 0, stream>>>(C16, stats2, bn2g, bn2b, owb2, o2b, flag, (const float*)nullptr,
                                            (u16*)nullptr, zacc, rw, rb, d_out, flag + 16);
}

// Round 6
// 258.133 us; speedup vs baseline: 1.1507x; 1.1507x over previous
//
#include <hip/hip_runtime.h>
#include <stdint.h>

typedef unsigned short u16;
typedef __attribute__((ext_vector_type(8))) short bf16x8;
typedef __attribute__((ext_vector_type(4))) float f32x4;

static const int N_NODES = 131072;   // B*T*NN = 128*128*8
static const int N_EDGES = 1048576;

__device__ __forceinline__ float u2f(u16 u){
  union{uint32_t i; float f;} w; w.i = ((uint32_t)u)<<16; return w.f;
}
__device__ __forceinline__ u16 f2u(float f){
  union{float f; uint32_t u;} v; v.f=f;
  uint32_t u=v.u;
  u += 0x7fff + ((u>>16)&1);   // round-to-nearest-even
  return (u16)(u>>16);
}
__device__ __forceinline__ float bits2f(uint32_t b){
  union{uint32_t i; float f;} w; w.i = b; return w.f;
}
__device__ __forceinline__ float ldmix(const void* p, int i, int isbf){
  return isbf ? u2f(((const u16*)p)[i]) : ((const float*)p)[i];
}
// fast tanh: 1 - 2/(e^{2|x|}+1), sign restored. err ~1e-7 << bf16 quantum.
__device__ __forceinline__ float ftanh(float x){
  float ax = fabsf(x);
  float e  = __expf(ax + ax);
  float r  = 1.f - __fdividef(2.f, e + 1.f);
  return copysignf(r, x);
}

// ---------------- hist + fused dtype-detect + accumulator zeroing ----------------
__global__ __launch_bounds__(256) void k_hist(const int* __restrict__ dst, int* __restrict__ H,
                                              const uint32_t* __restrict__ x, int* __restrict__ flag,
                                              float* __restrict__ stats1, float* __restrict__ stats2,
                                              float* __restrict__ zacc){
  __shared__ int h[256];
  __shared__ int dcnt;
  int tid = threadIdx.x;
  h[tid] = 0;
  if (blockIdx.x == 0){
    if (tid == 0) dcnt = 0;
    for (int i=tid; i<512; i+=256){ stats1[i] = 0.f; stats2[i] = 0.f; }
    for (int i=tid; i<1024; i+=256) zacc[i] = 0.f;
  }
  __syncthreads();
  if (blockIdx.x == 0){
    uint32_t e = (x[tid]>>7) & 0xFFu;
    int ok = (e >= 0x6Fu && e <= 0x85u) ? 1 : 0;
    unsigned long long m = __ballot(ok);
    if ((tid & 63) == 0) atomicAdd(&dcnt, (int)__popcll(m));
    __syncthreads();
    if (tid == 0) *flag = (dcnt >= 128) ? 1 : 0;
  }
  int base = blockIdx.x*4096;
  #pragma unroll
  for (int i=0;i<16;i++){
    int e2 = base + i*256 + tid;
    atomicAdd(&h[(dst[e2] & (N_NODES-1))>>9], 1);
  }
  __syncthreads();
  H[blockIdx.x*256 + tid] = h[tid];
}

// ---- combined weight-fold helper (unchanged math) ----
__device__ __forceinline__ void wcomb_one(int Kin, const void* gW, const void* gb, const void* tw,
                                          int isbf, u16* Wtb, float* braw, int r, int co){
  if (r < 3*Kin){
    int k = r / Kin, j = r - (r/Kin)*Kin;
    float acc = 0.f;
    for (int c=0; c<64; c++)
      acc += ldmix(gW, j*64+c, isbf) * ldmix(tw, co*192 + c*3 + k, isbf);
    Wtb[co*(3*Kin) + r] = f2u(acc);
  } else {
    int k = r - 3*Kin;
    float acc = 0.f;
    for (int c=0; c<64; c++)
      acc += ldmix(gb, c, isbf) * ldmix(tw, co*192 + c*3 + k, isbf);
    braw[k*64 + co] = acc;
  }
}

// ---------------- column scan (blocks 0..255) + weight-fold (blocks 256..361) ----------------
__global__ __launch_bounds__(256) void k_colscan_w(const int* __restrict__ H, int* __restrict__ P,
                                                   int* __restrict__ bt,
                                                   const void* __restrict__ g1w, const void* __restrict__ g1b,
                                                   const void* __restrict__ t1w,
                                                   const void* __restrict__ g2w, const void* __restrict__ g2b,
                                                   const void* __restrict__ t2w,
                                                   const void* __restrict__ o1w, const void* __restrict__ o2w,
                                                   const int* __restrict__ flag,
                                                   u16* __restrict__ Wtb1, float* __restrict__ braw1,
                                                   u16* __restrict__ Wtb2, float* __restrict__ braw2,
                                                   u16* __restrict__ owb1, u16* __restrict__ owb2){
  int tid = threadIdx.x;
  if (blockIdx.x < 256){
    __shared__ int sc[256];
    int b = blockIdx.x;
    int v = H[tid*256 + b];
    sc[tid] = v; __syncthreads();
    for (int d=1; d<256; d<<=1){
      int o = (tid>=d) ? sc[tid-d] : 0; __syncthreads();
      sc[tid] += o; __syncthreads();
    }
    P[tid*256 + b] = sc[tid] - v;
    if (tid==255) bt[b] = sc[255];
  } else {
    int isbf = *flag;
    int r = (blockIdx.x - 256)*4 + (tid>>6);
    int co = tid & 63;
    if (r >= 422) return;
    if (r < 99) wcomb_one(32, g1w, g1b, t1w, isbf, Wtb1, braw1, r, co);
    else if (r < 294) wcomb_one(64, g2w, g2b, t2w, isbf, Wtb2, braw2, r-99, co);
    else if (r < 358){
      int row = r - 294;
      owb1[row*64 + co] = f2u(ldmix(o1w, row*64 + co, isbf));
    } else {
      int row = r - 358;
      owb2[row*64 + co] = f2u(ldmix(o2w, row*64 + co, isbf));
    }
  }
}

__global__ __launch_bounds__(256) void k_scatter2(const int* __restrict__ src, const int* __restrict__ dst,
                                                  const int* __restrict__ P, const int* __restrict__ bt,
                                                  uint32_t* __restrict__ ebuf){
  __shared__ int cu[256], sc[256];
  int tid = threadIdx.x;
  int v = bt[tid];
  sc[tid] = v; __syncthreads();
  for (int d=1; d<256; d<<=1){
    int o = (tid>=d) ? sc[tid-d] : 0; __syncthreads();
    sc[tid] += o; __syncthreads();
  }
  cu[tid] = (sc[tid] - v) + P[blockIdx.x*256 + tid];   // bb[tid] + P
  __syncthreads();
  int base = blockIdx.x*4096;
  #pragma unroll
  for (int i=0;i<16;i++){
    int e = base + i*256 + tid;
    int s = src[e] & (N_NODES-1);
    int d = dst[e] & (N_NODES-1);
    int pos = atomicAdd(&cu[d>>9], 1);           // LDS atomic only
    ebuf[pos] = (uint32_t)s | ((uint32_t)(d & 511) << 17);
  }
}

// per-bucket counting sort + offs/deg/dinv + fused dinv-prescale of x -> bf16 (F=32)
__global__ __launch_bounds__(512) void k_bsort2(const uint32_t* __restrict__ ebuf, const int* __restrict__ bt,
                                                const void* __restrict__ x, const int* __restrict__ flag,
                                                int* __restrict__ adj, int* __restrict__ offs,
                                                int* __restrict__ deg, float* __restrict__ dinv,
                                                u16* __restrict__ Bout){
  __shared__ uint32_t ein[5120], outs[5120];
  __shared__ int hist[512], sc[512], cu[512];
  __shared__ int sct[256];
  __shared__ float dv[512];
  int b = blockIdx.x, tid = threadIdx.x;
  if (tid < 256){ sct[tid] = bt[tid]; }
  __syncthreads();
  for (int d=1; d<256; d<<=1){
    int o = (tid < 256 && tid>=d) ? sct[tid-d] : 0; __syncthreads();
    if (tid < 256) sct[tid] += o; __syncthreads();
  }
  int lo = sct[b] - bt[b], hi = sct[b];
  int cnt = hi - lo; if (cnt > 5120) cnt = 5120; if (cnt < 0) cnt = 0;
  hist[tid] = 0;
  __syncthreads();
  for (int i=tid; i<cnt; i+=512){
    uint32_t p = ebuf[lo+i];
    ein[i] = p;
    atomicAdd(&hist[(p>>17)&511], 1);
  }
  __syncthreads();
  sc[tid] = hist[tid];
  __syncthreads();
  for (int d=1; d<512; d<<=1){
    int v = (tid>=d) ? sc[tid-d] : 0;
    __syncthreads();
    sc[tid] += v;
    __syncthreads();
  }
  {
    int ex = sc[tid] - hist[tid];
    int node = b*512 + tid;
    offs[node] = lo + ex;
    deg[node]  = hist[tid];
    float rs = rsqrtf((float)hist[tid] + 1.0f);
    dinv[node] = rs;
    dv[tid] = rs;
    cu[tid] = ex;
  }
  __syncthreads();
  for (int i=tid; i<cnt; i+=512){
    uint32_t p = ein[i];
    int pos = atomicAdd(&cu[(p>>17)&511], 1);
    outs[pos] = p & 0x1FFFFu;
  }
  __syncthreads();
  for (int i=tid; i<cnt; i+=512) adj[lo+i] = (int)outs[i];
  int isbf = *flag;
  {
    uint32_t* Bd = (uint32_t*)Bout;
    for (int u=tid; u<8192; u+=512){
      int nl = u>>4, jd = u&15;                  // 16 u32-pairs per 32-col row
      int half = ((b<<9) + nl)*16 + jd;
      float x0, x1;
      if (isbf){
        uint32_t pr = ((const uint32_t*)x)[half];
        x0 = bits2f(pr<<16); x1 = bits2f(pr & 0xFFFF0000u);
      } else {
        float2 f2 = ((const float2*)x)[half];
        x0 = f2.x; x1 = f2.y;
      }
      float d = dv[nl];
      Bd[half] = (uint32_t)f2u(x0*d) | ((uint32_t)f2u(x1*d) << 16);
    }
  }
}

__device__ __forceinline__ void acc16(uint4 a, float* acc){
  acc[0] += bits2f(a.x<<16); acc[1] += bits2f(a.x&0xFFFF0000u);
  acc[2] += bits2f(a.y<<16); acc[3] += bits2f(a.y&0xFFFF0000u);
  acc[4] += bits2f(a.z<<16); acc[5] += bits2f(a.z&0xFFFF0000u);
  acc[6] += bits2f(a.w<<16); acc[7] += bits2f(a.w&0xFFFF0000u);
}

// =====================================================================================
// k_gconv: fused GCN-aggregate (direct into LDS At) + temporal-conv MFMA + BN stats.
// R6: launch_bounds(256,3) raises the VGPR cap to ~168 (vs compiler-default 60) so the
// 16-wide masked gather batch (av[16] = 64 VGPRs) can actually stay in flight.
// Occupancy target unchanged: 3 waves/SIMD = 12 waves/CU ~= the 35% measured at R4.
// =====================================================================================
template<int Kin>
__global__ __launch_bounds__(256, 3) void k_gconv(
    const u16* __restrict__ Xs, const int* __restrict__ adj, const int* __restrict__ offs,
    const int* __restrict__ deg, const float* __restrict__ dinv,
    const u16* __restrict__ Wtb, const float* __restrict__ braw, const void* __restrict__ tb,
    const int* __restrict__ flag, u16* __restrict__ out, float* __restrict__ stats){
  constexpr int K   = 3*Kin;
  constexpr int SA  = Kin + 8;
  constexpr int CH  = Kin/8;           // 16B chunks per row
  constexpr int GPW = 64/CH;           // rows per wave pass
  __shared__ alignas(16) u16 At[66*SA];
  __shared__ float ball[64], bs0[64], bs2[64];
  __shared__ float wsum[4][64], wsum2[4][64];

  int isbf = *flag;
  int bid = blockIdx.x;
  int b = bid>>4, rem = bid&15, v = rem>>1, th = rem&1;
  const int tid = threadIdx.x;
  int wv_ = tid >> 6, lane = tid & 63;
  int q = lane >> 4, l16 = lane & 15;
  int ltb0 = wv_ * 16;
  int g = lane / CH, kch = lane % CH;
  const uint4* X4 = (const uint4*)Xs;

  if (tid < 64){
    float b0=braw[tid], b1=braw[64+tid], b2=braw[128+tid];
    ball[tid] = ldmix(tb, tid, isbf) + b0 + b1 + b2;
    bs0[tid] = b0; bs2[tid] = b2;
  }

  // ---- fused aggregation: build At rows (bit-identical values to the split kernel) ----
  for (int row = wv_*GPW + g; row < 66; row += 4*GPW){
    int t = th*64 + row - 1;
    uint4 rv = {0,0,0,0};
    if (t >= 0 && t < 128){
      int n = (b*128 + t)*8 + v;
      int o = offs[n] & (N_EDGES-1);
      int cnt = min(deg[n], 8192);
      float dvv = dinv[n];
      float acc[8] = {0,0,0,0,0,0,0,0};
      acc16(X4[(size_t)n*CH + kch], acc);
      // fast path: one masked 16-wide MLP batch (single latency round)
      {
        int idx[16];
        #pragma unroll
        for (int j=0; j<16; j++){
          int ao = o + j; ao = (ao > N_EDGES-1) ? (N_EDGES-1) : ao;
          int ai = adj[ao] & (N_NODES-1);
          idx[j] = (j < cnt) ? ai : n;          // inactive -> self row (L1-hot)
        }
        uint4 av[16];
        #pragma unroll
        for (int j=0; j<16; j++) av[j] = X4[(size_t)idx[j]*CH + kch];
        #pragma unroll
        for (int j=0; j<16; j++){
          uint4 tv = av[j];
          bool act = (j < cnt);
          tv.x = act ? tv.x : 0u; tv.y = act ? tv.y : 0u;
          tv.z = act ? tv.z : 0u; tv.w = act ? tv.w : 0u;   // +0.0f adds are bit-exact
          acc16(tv, acc);
        }
      }
      int e = (cnt < 16) ? cnt : 16;
      // rare deg>16 continuation (verbatim old batch structure, same order)
      for (; e+8 <= cnt; e += 8){
        int i0 = adj[o+e+0] & (N_NODES-1);
        int i1 = adj[o+e+1] & (N_NODES-1);
        int i2 = adj[o+e+2] & (N_NODES-1);
        int i3 = adj[o+e+3] & (N_NODES-1);
        int i4 = adj[o+e+4] & (N_NODES-1);
        int i5 = adj[o+e+5] & (N_NODES-1);
        int i6 = adj[o+e+6] & (N_NODES-1);
        int i7 = adj[o+e+7] & (N_NODES-1);
        uint4 a0 = X4[(size_t)i0*CH + kch];
        uint4 a1 = X4[(size_t)i1*CH + kch];
        uint4 a2 = X4[(size_t)i2*CH + kch];
        uint4 a3 = X4[(size_t)i3*CH + kch];
        uint4 a4 = X4[(size_t)i4*CH + kch];
        uint4 a5 = X4[(size_t)i5*CH + kch];
        uint4 a6 = X4[(size_t)i6*CH + kch];
        uint4 a7 = X4[(size_t)i7*CH + kch];
        acc16(a0, acc); acc16(a1, acc); acc16(a2, acc); acc16(a3, acc);
        acc16(a4, acc); acc16(a5, acc); acc16(a6, acc); acc16(a7, acc);
      }
      if (e+4 <= cnt){
        int i0 = adj[o+e+0] & (N_NODES-1);
        int i1 = adj[o+e+1] & (N_NODES-1);
        int i2 = adj[o+e+2] & (N_NODES-1);
        int i3 = adj[o+e+3] & (N_NODES-1);
        uint4 a0 = X4[(size_t)i0*CH + kch];
        uint4 a1 = X4[(size_t)i1*CH + kch];
        uint4 a2 = X4[(size_t)i2*CH + kch];
        uint4 a3 = X4[(size_t)i3*CH + kch];
        acc16(a0, acc); acc16(a1, acc); acc16(a2, acc); acc16(a3, acc);
        e += 4;
      }
      for (; e < cnt; e++){
        int s = adj[o+e] & (N_NODES-1);
        uint4 a = X4[(size_t)s*CH + kch];
        acc16(a, acc);
      }
      rv.x = (uint32_t)f2u(acc[0]*dvv) | ((uint32_t)f2u(acc[1]*dvv) << 16);
      rv.y = (uint32_t)f2u(acc[2]*dvv) | ((uint32_t)f2u(acc[3]*dvv) << 16);
      rv.z = (uint32_t)f2u(acc[4]*dvv) | ((uint32_t)f2u(acc[5]*dvv) << 16);
      rv.w = (uint32_t)f2u(acc[6]*dvv) | ((uint32_t)f2u(acc[7]*dvv) << 16);
    }
    *(uint4*)&At[row*SA + kch*8] = rv;
  }
  __syncthreads();

  // ---- temporal-conv MFMA (verbatim from k_tconv3) ----
  f32x4 acc4[4];
  #pragma unroll
  for (int nt=0; nt<4; nt++) acc4[nt] = (f32x4){0.f,0.f,0.f,0.f};
  #pragma unroll
  for (int s=0; s<K/32; s++){
    int kk2 = (32*s)/Kin;
    int j0 = 32*s - kk2*Kin;
    int col = j0 + q*8;
    bf16x8 afr = *(const bf16x8*)&At[(ltb0 + l16 + kk2)*SA + col];
    bf16x8 bfr[4];
    #pragma unroll
    for (int nt=0; nt<4; nt++){
      int co = nt*16 + l16;
      bfr[nt] = *(const bf16x8*)&Wtb[co*K + 32*s + q*8];   // global, L1/L2-hot broadcast
    }
    #pragma unroll
    for (int nt=0; nt<4; nt++)
      acc4[nt] = __builtin_amdgcn_mfma_f32_16x16x32_bf16(afr, bfr[nt], acc4[nt], 0, 0, 0);
  }

  // ---- epilogue -> C16 (same bf16 round-trip) + BN stats ----
  float ls_[4] = {0,0,0,0}, ls2_[4] = {0,0,0,0};
  #pragma unroll
  for (int r=0; r<4; r++){
    int t = th*64 + ltb0 + q*4 + r;
    int base = (((b*128+t)*8+v)) << 6;
    #pragma unroll
    for (int nt=0; nt<4; nt++){
      int co = nt*16 + l16;
      float val = acc4[nt][r] + ball[co];
      if (t == 0)   val -= bs0[co];
      if (t == 127) val -= bs2[co];
      out[base + co] = f2u(val);
      ls_[nt] += val; ls2_[nt] += val*val;
    }
  }
  #pragma unroll
  for (int nt=0; nt<4; nt++){
    ls_[nt]  += __shfl_xor(ls_[nt], 16);  ls_[nt]  += __shfl_xor(ls_[nt], 32);
    ls2_[nt] += __shfl_xor(ls2_[nt], 16); ls2_[nt] += __shfl_xor(ls2_[nt], 32);
  }
  if (q == 0){
    #pragma unroll
    for (int nt=0; nt<4; nt++){
      wsum[wv_][nt*16 + l16]  = ls_[nt];
      wsum2[wv_][nt*16 + l16] = ls2_[nt];
    }
  }
  __syncthreads();
  if (tid < 64){
    float a = wsum[0][tid]+wsum[1][tid]+wsum[2][tid]+wsum[3][tid];
    float a2 = wsum2[0][tid]+wsum2[1][tid]+wsum2[2][tid]+wsum2[3][tid];
    int bank = (bid & 3) * 128;       // 4-way banked to cut atomic contention
    atomicAdd(&stats[bank + tid], a);
    atomicAdd(&stats[bank + 64 + tid], a2);
  }
}

// ---- BN-apply + ReLU + 1x1 conv via bf16 MFMA + tanh; grid 2048 (b,v,t-half) ----
template<bool FINAL>
__global__ __launch_bounds__(256) void k_bnfuse3(const u16* __restrict__ X, const float* __restrict__ stats,
                                                 const void* __restrict__ gam, const void* __restrict__ bet,
                                                 const u16* __restrict__ owb, const void* __restrict__ ob,
                                                 const int* __restrict__ flag, const float* __restrict__ presc,
                                                 u16* __restrict__ out16,
                                                 float* __restrict__ zacc, const void* __restrict__ rw){
  constexpr int SA = 72;
  __shared__ alignas(16) u16 Yl[64*SA];        // reused as Zl in epilogue
  __shared__ float kk[64], bsh[64], obs[64];
  __shared__ float rw_s[64];
  __shared__ float wred[4];
  int isbf = *flag;
  int bid = blockIdx.x;
  int b = bid>>4, rem = bid&15, v = rem>>1, th = rem&1;
  const int tid = threadIdx.x;
  const float invM = 1.0f/131072.0f;

  if (tid < 64){
    int ci = tid;
    float s1 = stats[ci] + stats[128+ci] + stats[256+ci] + stats[384+ci];
    float s2 = stats[64+ci] + stats[192+ci] + stats[320+ci] + stats[448+ci];
    float mu = s1*invM;
    float var = s2*invM - mu*mu;
    float rs = rsqrtf(fmaxf(var, 0.f) + 1e-5f);
    float kv = rs*ldmix(gam, ci, isbf);
    kk[ci] = kv;
    bsh[ci] = ldmix(bet, ci, isbf) - mu*kv;
    obs[ci] = ldmix(ob, ci, isbf);
    if (FINAL){
      float s = 0.f;
      #pragma unroll
      for (int f=0; f<8; f++) s += ldmix(rw, ci*8 + f, isbf);
      rw_s[ci] = s;
    }
  }
  __syncthreads();
  {
    uint32_t* Yd = (uint32_t*)Yl;
    const uint32_t* Xg = (const uint32_t*)X;
    for (int u=tid; u<64*32; u+=256){
      int lt = u>>5, jd = u&31;
      int ci = jd<<1;
      int t = th*64 + lt;
      int rowbase = (((b*128+t)*8+v)) << 6;
      uint32_t pr = Xg[(rowbase>>1) + jd];
      float x0 = bits2f(pr<<16);
      float x1 = bits2f(pr & 0xFFFF0000u);
      float y0 = fmaxf(x0*kk[ci] + bsh[ci], 0.f);
      float y1 = fmaxf(x1*kk[ci+1] + bsh[ci+1], 0.f);
      Yd[lt*(SA/2) + jd] = (uint32_t)f2u(y0) | ((uint32_t)f2u(y1) << 16);
    }
  }
  __syncthreads();

  int wv_ = tid >> 6, lane = tid & 63;
  int q = lane >> 4, l16 = lane & 15;
  int ltb0 = wv_ * 16;

  f32x4 acc[4];
  #pragma unroll
  for (int nt=0; nt<4; nt++) acc[nt] = (f32x4){0.f,0.f,0.f,0.f};

  #pragma unroll
  for (int s=0; s<2; s++){
    int col = 32*s + q*8;
    bf16x8 afr = *(const bf16x8*)&Yl[(ltb0 + l16)*SA + col];
    bf16x8 bfr[4];
    #pragma unroll
    for (int nt=0; nt<4; nt++){
      int co = nt*16 + l16;
      bfr[nt] = *(const bf16x8*)&owb[co*64 + col];   // global, L1/L2-hot broadcast
    }
    #pragma unroll
    for (int nt=0; nt<4; nt++)
      acc[nt] = __builtin_amdgcn_mfma_f32_16x16x32_bf16(afr, bfr[nt], acc[nt], 0, 0, 0);
  }

  __syncthreads();   // MFMA reads of Yl done; reuse as Zl
  #pragma unroll
  for (int r=0; r<4; r++){
    int lt = ltb0 + q*4 + r;
    #pragma unroll
    for (int nt=0; nt<4; nt++){
      int co = nt*16 + l16;
      Yl[lt*SA + co] = f2u(acc[nt][r] + obs[co]);
    }
  }
  __syncthreads();
  if (!FINAL){
    // element (co, l): from t = th*64 + l; write row r = b*1024+co*16+v*2+th, col l
    for (int u=tid; u<4096; u+=256){
      int l = u & 63;
      int co = u >> 6;
      float z = ftanh(u2f(Yl[l*SA + co]));
      int r = (b<<10) + (co<<4) + (v<<1) + th;
      if (presc) z *= presc[r];       // lane-uniform
      out16[(r<<6) + l] = f2u(z);
    }
  } else {
    float zsum = 0.f;
    for (int u=tid; u<4096; u+=256){
      int l = u & 63;
      int co = u >> 6;
      float z = ftanh(u2f(Yl[l*SA + co]));
      zsum += z * rw_s[l];
    }
    for (int off=32; off; off>>=1) zsum += __shfl_down(zsum, off);
    if (lane == 0) wred[wv_] = zsum;
    __syncthreads();
    if (tid == 0){
      int base = (b<<3) + ((v&3)<<1) + th;
      atomicAdd(&zacc[base], wred[0] + wred[1] + wred[2] + wred[3]);
    }
  }
}

// ---- finish: out[i] = zacc[i]/1024 + sum(rb)/8 ----
__global__ __launch_bounds__(256) void k_fin2(const float* __restrict__ zacc, const void* __restrict__ rb,
                                              const int* __restrict__ flag, void* __restrict__ out){
  int i = blockIdx.x*256 + threadIdx.x;
  if (i >= 1024) return;
  int isbf = *flag;
  float rbs = 0.f;
  #pragma unroll
  for (int f=0; f<8; f++) rbs += ldmix(rb, f, isbf);
  float val = zacc[i]*(1.0f/1024.0f) + rbs*0.125f;
  if (isbf) ((u16*)out)[i] = f2u(val);
  else      ((float*)out)[i] = val;
}

extern "C" void kernel_launch(void* const* d_in, const int* in_sizes, int n_in,
                              void* d_out, int out_size, void* d_ws, size_t ws_size,
                              hipStream_t stream){
  (void)in_sizes; (void)n_in; (void)out_size; (void)ws_size;
  char* p = (char*)d_ws;
  auto alloc = [&](size_t bytes){ void* r = (void*)p; p += (bytes + 255) & ~(size_t)255; return r; };
  u16*   U1   = (u16*)  alloc(sizeof(u16)*(size_t)N_NODES*64);  // Bs16 ; later D16
  u16*   U2   = (u16*)  alloc(sizeof(u16)*(size_t)N_NODES*64);  // (unused, kept for layout)
  u16*   C16  = (u16*)  alloc(sizeof(u16)*(size_t)N_NODES*64);  // tconv out (bf16); ebuf alias
  int*   deg  = (int*)  alloc(sizeof(int)*N_NODES);
  float* dinv = (float*)alloc(sizeof(float)*N_NODES);
  int*   offs = (int*)  alloc(sizeof(int)*N_NODES);
  int*   adj  = (int*)  alloc(sizeof(int)*N_EDGES);
  int*   H    = (int*)  alloc(sizeof(int)*256*256);
  int*   P    = (int*)  alloc(sizeof(int)*256*256);
  int*   bt   = (int*)  alloc(sizeof(int)*256);
  float* stats1=(float*)alloc(sizeof(float)*512);
  float* stats2=(float*)alloc(sizeof(float)*512);
  int*   flag = (int*)  alloc(sizeof(int)*64);
  u16*   Wtb1 = (u16*)  alloc(sizeof(u16)*96*64);
  float* braw1= (float*)alloc(sizeof(float)*192);
  u16*   Wtb2 = (u16*)  alloc(sizeof(u16)*192*64);
  float* braw2= (float*)alloc(sizeof(float)*192);
  u16*   owb1 = (u16*)  alloc(sizeof(u16)*64*64);
  u16*   owb2 = (u16*)  alloc(sizeof(u16)*64*64);
  float* zacc = (float*)alloc(sizeof(float)*1024);
  uint32_t* ebuf = (uint32_t*)C16;           // alias: C16 dead until gconv1
  u16* Bs16 = U1;                            // N x 32 bf16 (prescaled x)
  u16* D16  = U1;                            // N x 64 bf16 (bnfuse1 out, prescaled; Bs16 dead by then)
  (void)U2;

  const void* x   = d_in[0];
  const int* edge = (const int*)d_in[1];
  const void* g1w = d_in[2];  const void* g1b = d_in[3];
  const void* t1w = d_in[4];  const void* t1b = d_in[5];
  const void* bn1g= d_in[6];  const void* bn1b= d_in[7];
  const void* o1w = d_in[8];  const void* o1b = d_in[9];
  const void* g2w = d_in[10]; const void* g2b = d_in[11];
  const void* t2w = d_in[12]; const void* t2b = d_in[13];
  const void* bn2g= d_in[14]; const void* bn2b= d_in[15];
  const void* o2w = d_in[16]; const void* o2b = d_in[17];
  const void* rw  = d_in[18]; const void* rb  = d_in[19];
  const int* src = edge;
  const int* dst = edge + N_EDGES;

  // graph prep
  k_hist     <<<256, 256, 0, stream>>>(dst, H, (const uint32_t*)x, flag, stats1, stats2, zacc);
  k_colscan_w<<<362, 256, 0, stream>>>(H, P, bt, g1w, g1b, t1w, g2w, g2b, t2w, o1w, o2w, flag,
                                       Wtb1, braw1, Wtb2, braw2, owb1, owb2);
  k_scatter2 <<<256, 256, 0, stream>>>(src, dst, P, bt, ebuf);
  k_bsort2   <<<256, 512, 0, stream>>>(ebuf, bt, x, flag, adj, offs, deg, dinv, Bs16);

  // ---- layer 1: fused agg+tconv, then BN+1x1+tanh ----
  k_gconv<32> <<<2048, 256, 0, stream>>>(Bs16, adj, offs, deg, dinv, Wtb1, braw1, t1b, flag, C16, stats1);
  k_bnfuse3<false><<<2048, 256, 0, stream>>>(C16, stats1, bn1g, bn1b, owb1, o1b, flag, dinv, D16,
                                             (float*)nullptr, (const void*)nullptr);

  // ---- layer 2: fused agg+tconv, then BN+1x1+tanh+reduce ----
  k_gconv<64> <<<2048, 256, 0, stream>>>(D16, adj, offs, deg, dinv, Wtb2, braw2, t2b, flag, C16, stats2);
  k_bnfuse3<true><<<2048, 256, 0, stream>>>(C16, stats2, bn2g, bn2b, owb2, o2b, flag, (const float*)nullptr,
                                            (u16*)nullptr, zacc, rw);
  k_fin2<<<4, 256, 0, stream>>>(zacc, rb, flag, d_out);
}